// Round 1
// baseline (8516.463 us; speedup 1.0000x reference)
//
#include <hip/hip_runtime.h>

typedef unsigned int uint;
typedef unsigned short ushort_t;

#define NB 512      // batch
#define NK 1152     // input capsules
#define ND 8        // in dim
#define NU 16       // out dim
#define NJ 10       // output capsules
#define NPH 30      // routing phases (NJ * 3)
#define EPSQ 1e-7f

#define KT 36       // k per tile
#define KCN 32      // k chunks; kc = blockIdx&31 -> XCD = kc%8
#define BT 16       // b per tile
#define BGN 32      // b groups
#define XPH 296     // x tile pitch per b, in bf16 elems (288 + 8 pad -> 2-way banks)
#define WPH 136     // w tile pitch per k, in bf16 elems (128 + 8 pad -> 2-way banks)
#define SREDP 20    // part cross-wave reduce pitch (floats)
#define SVP 20      // agp sv pitch (floats, 16B-stride-aligned)

// ws layout (floats)
#define OFF_BL 0                        // b_logits [NK][NJ]      11520
#define OFF_S  11520                    // s [NPH][NB][NU]        245760
#define OFF_XB 257280                   // Xb bf16 [NB][NK][ND]   (2359296 floats)
#define OFF_WTB (OFF_XB + (NB*NK*ND)/2) // WTb bf16 [NJ][NK][NU][ND] (737280 floats)
#define OFF_CNT (OFF_WTB + (NJ*NK*NU*ND)/2) // barrier counters (ints)
#define NCNT (NPH * (BGN + KCN))        // 1920 ints
// total ~13.4 MB << ws

// fp32 -> bf16 RNE (values are finite/normal here)
__device__ __forceinline__ ushort_t b16(float f) {
  uint u = __float_as_uint(f);
  return (ushort_t)((u + 0x7fffu + ((u >> 16) & 1u)) >> 16);
}
// unpack 8 bf16 (uint4) -> 8 fp32
__device__ __forceinline__ void up8(const uint4 v, float* f) {
  f[0] = __uint_as_float(v.x << 16); f[1] = __uint_as_float(v.x & 0xffff0000u);
  f[2] = __uint_as_float(v.y << 16); f[3] = __uint_as_float(v.y & 0xffff0000u);
  f[4] = __uint_as_float(v.z << 16); f[5] = __uint_as_float(v.z & 0xffff0000u);
  f[6] = __uint_as_float(v.w << 16); f[7] = __uint_as_float(v.w & 0xffff0000u);
}
__device__ __forceinline__ float dot8(const float* a, const float* b) {
  return a[0]*b[0] + a[1]*b[1] + a[2]*b[2] + a[3]*b[3] +
         a[4]*b[4] + a[5]*b[5] + a[6]*b[6] + a[7]*b[7];
}

// 32-block partial barrier on a per-phase counter (never reused -> no reset
// hazard). Data written before arrival is published by the RELEASE add; the
// ACQUIRE poll + __syncthreads orders the whole block after all 32 releases.
__device__ __forceinline__ void gbar(int* c) {
  __syncthreads();  // all threads' atomics drained (vmcnt(0) before s_barrier)
  if (threadIdx.x == 0) {
    __threadfence();
    __hip_atomic_fetch_add(c, 1, __ATOMIC_RELEASE, __HIP_MEMORY_SCOPE_AGENT);
    int it = 0;
    while (__hip_atomic_load(c, __ATOMIC_ACQUIRE, __HIP_MEMORY_SCOPE_AGENT) < 32) {
      __builtin_amdgcn_s_sleep(2);
      if (++it > (1 << 24)) break;  // safety valve: wrong-answer beats hang
    }
  }
  __syncthreads();
}

// ---------------------------------------------------------------------------
// init: zero bl + s + barrier counters; build Xb[b][k][d] (bf16) and
// WTb[j][k][u][d] (bf16)
// ---------------------------------------------------------------------------
__global__ __launch_bounds__(256) void caps_init(const float* __restrict__ x,
                                                 const float* __restrict__ W,
                                                 float* __restrict__ bl,
                                                 float* __restrict__ s,
                                                 ushort_t* __restrict__ Xb,
                                                 ushort_t* __restrict__ WTb,
                                                 int* __restrict__ cnt) {
  const int g = blockIdx.x * 256 + threadIdx.x;
  if (g < NK * NJ) bl[g] = 0.f;
  if (g < NPH * NB * NU) s[g] = 0.f;
  if (g < NCNT) cnt[g] = 0;
  if (g < (NB * NK * ND) / 8) {  // 589824 groups of 8
    const float4* xp = (const float4*)x + (size_t)g * 2;
    const float4 a = xp[0], b = xp[1];
    uint4 o;
    o.x = (uint)b16(a.x) | ((uint)b16(a.y) << 16);
    o.y = (uint)b16(a.z) | ((uint)b16(a.w) << 16);
    o.z = (uint)b16(b.x) | ((uint)b16(b.y) << 16);
    o.w = (uint)b16(b.z) | ((uint)b16(b.w) << 16);
    ((uint4*)Xb)[g] = o;
  }
  if (g < (NJ * NK * NU * ND) / 8) {  // 184320 groups: (j,k,u) rows of 8 d
    const int u = g & 15;
    const int k = (g >> 4) % NK;
    const int j = g / (NK * NU);
    const float* wp = W + ((size_t)(j * NK + k) * ND) * NU + u;  // d-stride NU
    uint4 o;
    o.x = (uint)b16(wp[0])  | ((uint)b16(wp[16]) << 16);
    o.y = (uint)b16(wp[32]) | ((uint)b16(wp[48]) << 16);
    o.z = (uint)b16(wp[64]) | ((uint)b16(wp[80]) << 16);
    o.w = (uint)b16(wp[96]) | ((uint)b16(wp[112]) << 16);
    ((uint4*)WTb)[g] = o;
  }
}

// ---------------------------------------------------------------------------
// caps_main: persistent cooperative kernel. 1024 blocks (4/CU), block
// (kc,bgi) owns the 16b x 36k tile. X staged to LDS ONCE, W once per j.
// Per phase n=(j,t): softmax(bl col j) -> partial s (atomic) -> bgi-group
// barrier -> squash -> agree (atomic bl) -> kc-group barrier.
// Dependence coloring: s[b][u] couples only same-bgi blocks (32);
// bl[k][j] couples only same-kc blocks (32, all on one XCD).
// ---------------------------------------------------------------------------
__global__ __launch_bounds__(256, 4) void caps_main(
    const ushort_t* __restrict__ Xb, const ushort_t* __restrict__ WTb,
    float* __restrict__ bl, float* __restrict__ s, float* __restrict__ out,
    int* __restrict__ cs, int* __restrict__ cb) {
  __shared__ __align__(16) ushort_t sxu[BT * XPH];  // 9472 B, persistent
  __shared__ __align__(16) ushort_t swu[KT * WPH];  // 9792 B, per-j
  __shared__ float sc[KT];
  __shared__ float svbuf[BT * SVP];                 // 1280 B
  __shared__ float sred[4 * BT * SREDP];            // 5120 B
  const int tid = threadIdx.x;
  const int kc = blockIdx.x & (KCN - 1);
  const int bgi = blockIdx.x >> 5;
  const int b0 = bgi * BT;
  const int k0 = kc * KT;

  {  // stage x ONCE: 576 uint4 (one per (b,k))
    const uint4* gx = (const uint4*)Xb + ((size_t)b0 * NK + k0);
    for (int i = tid; i < BT * KT; i += 256) {
      const int b = i / KT, q = i - b * KT;
      *(uint4*)&sxu[b * XPH + q * 8] = gx[(size_t)b * NK + q];
    }
  }

  const int w = tid >> 6;
  const int lane = tid & 63;
  const int kq = lane >> 4;
  const int bq = (lane >> 2) & 3;
  const int uq = lane & 3;

  for (int n = 0; n < NPH; ++n) {
    const int j = n / 3;
    const int t = n - 3 * j;
    float* sn = s + (size_t)n * NB * NU;

    if (tid < KT) {  // softmax of bl row (k0+tid), column j. Coherent loads:
      // bl was updated by other blocks' agent-scope atomics (L2-bypassing);
      // plain loads could hit a stale local line.
      const float* row = bl + (size_t)(k0 + tid) * NJ;
      float r[NJ];
#pragma unroll
      for (int jj = 0; jj < NJ; ++jj)
        r[jj] = __hip_atomic_load(&row[jj], __ATOMIC_RELAXED,
                                  __HIP_MEMORY_SCOPE_AGENT);
      float mx = r[0];
#pragma unroll
      for (int jj = 1; jj < NJ; ++jj) mx = fmaxf(mx, r[jj]);
      float se = 0.f;
#pragma unroll
      for (int jj = 0; jj < NJ; ++jj) se += __expf(r[jj] - mx);
      sc[tid] = __expf(r[j] - mx) / se;
    }
    if (t == 0) {  // stage W for new j (swu persists across t=1,2)
      const uint4* gw = (const uint4*)WTb + ((size_t)j * NK + k0) * NU;
      for (int i = tid; i < KT * NU; i += 256) {
        const int k = i >> 4, u = i & 15;
        *(uint4*)&swu[k * WPH + u * 8] = gw[i];
      }
    }
    __syncthreads();

    // ---- part: partial s for this (kc,bgi) tile
    float a[4][4];
#pragma unroll
    for (int i = 0; i < 4; ++i)
#pragma unroll
      for (int m = 0; m < 4; ++m) a[i][m] = 0.f;
#pragma unroll
    for (int it = 0; it < 3; ++it) {
      const int kli = it * 4 + kq;
      if (kli < 9) {
        const int kl = w * 9 + kli;
        const float ck = sc[kl];
        float xd[4][8];
#pragma unroll
        for (int i = 0; i < 4; ++i)
          up8(*(const uint4*)&sxu[(bq * 4 + i) * XPH + kl * 8], xd[i]);
#pragma unroll
        for (int m = 0; m < 4; ++m) {
          float wd[8];
          up8(*(const uint4*)&swu[kl * WPH + (uq * 4 + m) * 8], wd);
#pragma unroll
          for (int i = 0; i < 4; ++i)
            a[i][m] = fmaf(ck, dot8(xd[i], wd), a[i][m]);
        }
      }
    }
#pragma unroll
    for (int i = 0; i < 4; ++i)
#pragma unroll
      for (int m = 0; m < 4; ++m) {
        a[i][m] += __shfl_xor(a[i][m], 16, 64);
        a[i][m] += __shfl_xor(a[i][m], 32, 64);
      }
    if (kq == 0) {
#pragma unroll
      for (int i = 0; i < 4; ++i) {
        const float4 t4 = {a[i][0], a[i][1], a[i][2], a[i][3]};
        *(float4*)&sred[(w * BT + bq * 4 + i) * SREDP + uq * 4] = t4;
      }
    }
    __syncthreads();
    {  // sum 4 waves; accumulate into this phase's s buffer
      const int b = tid >> 4, u = tid & 15;
      const float pv =
          sred[(0 * BT + b) * SREDP + u] + sred[(1 * BT + b) * SREDP + u] +
          sred[(2 * BT + b) * SREDP + u] + sred[(3 * BT + b) * SREDP + u];
      atomicAdd(&sn[(size_t)(b0 + b) * NU + u], pv);
    }
    gbar(&cs[n * BGN + bgi]);  // s complete for this b-slice

    {  // squash: v from completed s (coherent loads; atomics bypassed L1/L2)
      const int b = tid >> 4, u = tid & 15;
      const float sval = __hip_atomic_load(&sn[(size_t)(b0 + b) * NU + u],
                                           __ATOMIC_RELAXED,
                                           __HIP_MEMORY_SCOPE_AGENT);
      float sq = sval * sval;
      sq += __shfl_xor(sq, 1, 64);
      sq += __shfl_xor(sq, 2, 64);
      sq += __shfl_xor(sq, 4, 64);
      sq += __shfl_xor(sq, 8, 64);
      const float scale = (sq / (1.f + sq)) / (sqrtf(sq) + EPSQ);
      const float vv = scale * sval;
      svbuf[b * SVP + u] = vv;
      if (t == 2 && kc == 0)
        out[((size_t)(b0 + b) * NJ + j) * NU + u] = vv;
    }
    __syncthreads();

    if (n < NPH - 1) {  // agree (column j, same swu); skip at n=29 (dead)
      float4 vf[4];
#pragma unroll
      for (int i = 0; i < 4; ++i)
        vf[i] = *(const float4*)&svbuf[(bq * 4 + i) * SVP + uq * 4];
#pragma unroll
      for (int it = 0; it < 3; ++it) {
        const int kli = it * 4 + kq;
        if (kli < 9) {
          const int kl = w * 9 + kli;
          float xd[4][8];
#pragma unroll
          for (int i = 0; i < 4; ++i)
            up8(*(const uint4*)&sxu[(bq * 4 + i) * XPH + kl * 8], xd[i]);
          float ag = 0.f;
#pragma unroll
          for (int m = 0; m < 4; ++m) {
            float wd[8];
            up8(*(const uint4*)&swu[kl * WPH + (uq * 4 + m) * 8], wd);
#pragma unroll
            for (int i = 0; i < 4; ++i) {
              const float vm = (m == 0) ? vf[i].x
                             : (m == 1) ? vf[i].y
                             : (m == 2) ? vf[i].z : vf[i].w;
              ag = fmaf(vm, dot8(xd[i], wd), ag);
            }
          }
          ag += __shfl_xor(ag, 1, 64);
          ag += __shfl_xor(ag, 2, 64);
          ag += __shfl_xor(ag, 4, 64);
          ag += __shfl_xor(ag, 8, 64);
          if ((lane & 15) == 0)
            atomicAdd(&bl[(size_t)(k0 + kl) * NJ + j], ag);
        }
      }
      gbar(&cb[n * KCN + kc]);  // bl column j complete for this k-slice
    }
  }
}

// ---------------------------------------------------------------------------
// Fallback path kernels (previous proven 59-launch version), used only if
// cooperative launch is rejected (e.g. unsupported under graph capture).
// ---------------------------------------------------------------------------
__global__ __launch_bounds__(256, 4) void caps_part(
    const ushort_t* __restrict__ Xb, const ushort_t* __restrict__ WTb,
    const float* __restrict__ bl, float* __restrict__ sn, int js) {
  __shared__ __align__(16) ushort_t sxu[BT * XPH];
  __shared__ __align__(16) ushort_t swu[KT * WPH];
  __shared__ float sc[KT];
  float* sred = (float*)sxu;
  const int tid = threadIdx.x;
  const int kc = blockIdx.x & (KCN - 1);
  const int bgi = blockIdx.x >> 5;
  const int b0 = bgi * BT;
  const int k0 = kc * KT;
  {
    const uint4* gx = (const uint4*)Xb + ((size_t)b0 * NK + k0);
    for (int i = tid; i < BT * KT; i += 256) {
      const int b = i / KT, q = i - b * KT;
      *(uint4*)&sxu[b * XPH + q * 8] = gx[(size_t)b * NK + q];
    }
  }
  {
    const uint4* gw = (const uint4*)WTb + ((size_t)js * NK + k0) * NU;
    for (int i = tid; i < KT * NU; i += 256) {
      const int k = i >> 4, u = i & 15;
      *(uint4*)&swu[k * WPH + u * 8] = gw[i];
    }
  }
  if (tid < KT) {
    const float* row = bl + (size_t)(k0 + tid) * NJ;
    float r[NJ];
#pragma unroll
    for (int jj = 0; jj < NJ; ++jj) r[jj] = row[jj];
    float mx = r[0];
#pragma unroll
    for (int jj = 1; jj < NJ; ++jj) mx = fmaxf(mx, r[jj]);
    float se = 0.f;
#pragma unroll
    for (int jj = 0; jj < NJ; ++jj) se += __expf(r[jj] - mx);
    sc[tid] = __expf(r[js] - mx) / se;
  }
  __syncthreads();
  const int w = tid >> 6;
  const int lane = tid & 63;
  const int kq = lane >> 4;
  const int bq = (lane >> 2) & 3;
  const int uq = lane & 3;
  float a[4][4];
#pragma unroll
  for (int i = 0; i < 4; ++i)
#pragma unroll
    for (int m = 0; m < 4; ++m) a[i][m] = 0.f;
#pragma unroll
  for (int it = 0; it < 3; ++it) {
    const int kli = it * 4 + kq;
    if (kli < 9) {
      const int kl = w * 9 + kli;
      const float ck = sc[kl];
      float xd[4][8];
#pragma unroll
      for (int i = 0; i < 4; ++i)
        up8(*(const uint4*)&sxu[(bq * 4 + i) * XPH + kl * 8], xd[i]);
#pragma unroll
      for (int m = 0; m < 4; ++m) {
        float wd[8];
        up8(*(const uint4*)&swu[kl * WPH + (uq * 4 + m) * 8], wd);
#pragma unroll
        for (int i = 0; i < 4; ++i)
          a[i][m] = fmaf(ck, dot8(xd[i], wd), a[i][m]);
      }
    }
  }
#pragma unroll
  for (int i = 0; i < 4; ++i)
#pragma unroll
    for (int m = 0; m < 4; ++m) {
      a[i][m] += __shfl_xor(a[i][m], 16, 64);
      a[i][m] += __shfl_xor(a[i][m], 32, 64);
    }
  __syncthreads();
  if (kq == 0) {
#pragma unroll
    for (int i = 0; i < 4; ++i) {
      const float4 t4 = {a[i][0], a[i][1], a[i][2], a[i][3]};
      *(float4*)&sred[(w * BT + bq * 4 + i) * SREDP + uq * 4] = t4;
    }
  }
  __syncthreads();
  {
    const int b = tid >> 4, u = tid & 15;
    const float sv =
        sred[(0 * BT + b) * SREDP + u] + sred[(1 * BT + b) * SREDP + u] +
        sred[(2 * BT + b) * SREDP + u] + sred[(3 * BT + b) * SREDP + u];
    atomicAdd(&sn[(size_t)(b0 + b) * NU + u], sv);
  }
}

__global__ __launch_bounds__(256, 4) void caps_agp(
    const ushort_t* __restrict__ Xb, const ushort_t* __restrict__ WTb,
    const float* __restrict__ sprev, float* __restrict__ bl,
    float* __restrict__ out, int ja, int wout) {
  __shared__ __align__(16) ushort_t sxu[BT * XPH];
  __shared__ __align__(16) ushort_t swu[KT * WPH];
  __shared__ float sv[BT * SVP];
  const int tid = threadIdx.x;
  const int kc = blockIdx.x & (KCN - 1);
  const int bgi = blockIdx.x >> 5;
  const int b0 = bgi * BT;
  const int k0 = kc * KT;
  {
    const uint4* gx = (const uint4*)Xb + ((size_t)b0 * NK + k0);
    for (int i = tid; i < BT * KT; i += 256) {
      const int b = i / KT, q = i - b * KT;
      *(uint4*)&sxu[b * XPH + q * 8] = gx[(size_t)b * NK + q];
    }
  }
  {
    const uint4* gw = (const uint4*)WTb + ((size_t)ja * NK + k0) * NU;
    for (int i = tid; i < KT * NU; i += 256) {
      const int k = i >> 4, u = i & 15;
      *(uint4*)&swu[k * WPH + u * 8] = gw[i];
    }
  }
  {
    const int b = tid >> 4, u = tid & 15;
    const float s = sprev[(size_t)(b0 + b) * NU + u];
    float sq = s * s;
    sq += __shfl_xor(sq, 1, 64);
    sq += __shfl_xor(sq, 2, 64);
    sq += __shfl_xor(sq, 4, 64);
    sq += __shfl_xor(sq, 8, 64);
    const float scale = (sq / (1.f + sq)) / (sqrtf(sq) + EPSQ);
    const float vv = scale * s;
    sv[b * SVP + u] = vv;
    if (wout && kc == 0) out[((size_t)(b0 + b) * NJ + ja) * NU + u] = vv;
  }
  __syncthreads();
  const int w = tid >> 6;
  const int lane = tid & 63;
  const int kq = lane >> 4;
  const int bq = (lane >> 2) & 3;
  const int uq = lane & 3;
  float4 vf[4];
#pragma unroll
  for (int i = 0; i < 4; ++i)
    vf[i] = *(const float4*)&sv[(bq * 4 + i) * SVP + uq * 4];
#pragma unroll
  for (int it = 0; it < 3; ++it) {
    const int kli = it * 4 + kq;
    if (kli < 9) {
      const int kl = w * 9 + kli;
      float xd[4][8];
#pragma unroll
      for (int i = 0; i < 4; ++i)
        up8(*(const uint4*)&sxu[(bq * 4 + i) * XPH + kl * 8], xd[i]);
      float ag = 0.f;
#pragma unroll
      for (int m = 0; m < 4; ++m) {
        float wd[8];
        up8(*(const uint4*)&swu[kl * WPH + (uq * 4 + m) * 8], wd);
#pragma unroll
        for (int i = 0; i < 4; ++i) {
          const float vm = (m == 0) ? vf[i].x
                         : (m == 1) ? vf[i].y
                         : (m == 2) ? vf[i].z : vf[i].w;
          ag = fmaf(vm, dot8(xd[i], wd), ag);
        }
      }
      ag += __shfl_xor(ag, 1, 64);
      ag += __shfl_xor(ag, 2, 64);
      ag += __shfl_xor(ag, 4, 64);
      ag += __shfl_xor(ag, 8, 64);
      if ((lane & 15) == 0)
        atomicAdd(&bl[(size_t)(k0 + kl) * NJ + ja], ag);
    }
  }
}

__global__ __launch_bounds__(256) void caps_finout(const float* __restrict__ slast,
                                                   float* __restrict__ out) {
  const int g = blockIdx.x * 256 + threadIdx.x;
  const int b = g >> 4, u = g & 15;
  const float s = slast[(size_t)b * NU + u];
  float sq = s * s;
  sq += __shfl_xor(sq, 1, 64);
  sq += __shfl_xor(sq, 2, 64);
  sq += __shfl_xor(sq, 4, 64);
  sq += __shfl_xor(sq, 8, 64);
  const float scale = (sq / (1.f + sq)) / (sqrtf(sq) + EPSQ);
  out[((size_t)b * NJ + (NJ - 1)) * NU + u] = scale * s;
}

// ---------------------------------------------------------------------------
extern "C" void kernel_launch(void* const* d_in, const int* in_sizes, int n_in,
                              void* d_out, int out_size, void* d_ws,
                              size_t ws_size, hipStream_t stream) {
  (void)in_sizes; (void)n_in; (void)out_size; (void)ws_size;
  const float* x = (const float*)d_in[0];   // [512][1152][8][1] fp32
  const float* W = (const float*)d_in[1];   // [10][1152][8][16] fp32
  float* out = (float*)d_out;               // [512][10][16][1] fp32
  float* ws = (float*)d_ws;
  float* bl = ws + OFF_BL;
  float* s  = ws + OFF_S;
  ushort_t* Xb  = (ushort_t*)(ws + OFF_XB);
  ushort_t* WTb = (ushort_t*)(ws + OFF_WTB);
  int* cs = (int*)(ws + OFF_CNT);           // [NPH][BGN]
  int* cb = cs + NPH * BGN;                 // [NPH][KCN]

  caps_init<<<(NB * NK * ND / 8 + 255) / 256, 256, 0, stream>>>(x, W, bl, s,
                                                                Xb, WTb, cs);

  void* args[] = {&Xb, &WTb, &bl, &s, &out, &cs, &cb};
  hipError_t err = hipLaunchCooperativeKernel(
      (const void*)caps_main, dim3(KCN * BGN), dim3(256), args, 0, stream);

  if (err != hipSuccess) {
    // Fallback: proven 59-launch sequence (identical numerics).
    for (int n = 0; n < NPH; ++n) {
      const int j = n / 3, t = n - 3 * j;
      if (n > 0) {
        const int ja = (t == 0) ? (j - 1) : j;
        caps_agp<<<KCN * BGN, 256, 0, stream>>>(
            Xb, WTb, s + (size_t)(n - 1) * NB * NU, bl, out, ja,
            (t == 0) ? 1 : 0);
      }
      caps_part<<<KCN * BGN, 256, 0, stream>>>(Xb, WTb, bl,
                                               s + (size_t)n * NB * NU, j);
    }
    caps_finout<<<(NB * NU) / 256, 256, 0, stream>>>(
        s + (size_t)(NPH - 1) * NB * NU, out);
  }
}

// Round 2
// 3340.588 us; speedup vs baseline: 2.5494x; 2.5494x over previous
//
#include <hip/hip_runtime.h>

typedef unsigned int uint;
typedef unsigned short ushort_t;

#define NB 512      // batch
#define NK 1152     // input capsules
#define ND 8        // in dim
#define NU 16       // out dim
#define NJ 10       // output capsules
#define NPH 30      // routing phases (NJ * 3)
#define EPSQ 1e-7f

#define KT 36       // k per tile
#define KCN 32      // k chunks; kc = blockIdx&31 -> XCD = kc%8
#define BT 16       // b per tile
#define BGN 32      // b groups
#define XPH 296     // x tile pitch per b, in bf16 elems (288 + 8 pad -> 2-way banks)
#define WPH 136     // w tile pitch per k, in bf16 elems (128 + 8 pad -> 2-way banks)
#define SREDP 20    // part cross-wave reduce pitch (floats)
#define SVP 20      // agp sv pitch (floats, 16B-stride-aligned)

// ws layout (floats)
#define OFF_BL 0                        // b_logits [NK][NJ]      11520
#define OFF_S  11520                    // s [NPH][NB][NU]        245760
#define OFF_XB 257280                   // Xb bf16 [NB][NK][ND]   (2359296 floats)
#define OFF_WTB (OFF_XB + (NB*NK*ND)/2) // WTb bf16 [NJ][NK][NU][ND] (737280 floats)
#define OFF_CNT (OFF_WTB + (NJ*NK*NU*ND)/2) // barrier counters (ints)
#define NCNT (NPH * (BGN + KCN))        // 1920 ints
// total ~13.4 MB << ws

// fp32 -> bf16 RNE (values are finite/normal here)
__device__ __forceinline__ ushort_t b16(float f) {
  uint u = __float_as_uint(f);
  return (ushort_t)((u + 0x7fffu + ((u >> 16) & 1u)) >> 16);
}
// unpack 8 bf16 (uint4) -> 8 fp32
__device__ __forceinline__ void up8(const uint4 v, float* f) {
  f[0] = __uint_as_float(v.x << 16); f[1] = __uint_as_float(v.x & 0xffff0000u);
  f[2] = __uint_as_float(v.y << 16); f[3] = __uint_as_float(v.y & 0xffff0000u);
  f[4] = __uint_as_float(v.z << 16); f[5] = __uint_as_float(v.z & 0xffff0000u);
  f[6] = __uint_as_float(v.w << 16); f[7] = __uint_as_float(v.w & 0xffff0000u);
}
__device__ __forceinline__ float dot8(const float* a, const float* b) {
  return a[0]*b[0] + a[1]*b[1] + a[2]*b[2] + a[3]*b[3] +
         a[4]*b[4] + a[5]*b[5] + a[6]*b[6] + a[7]*b[7];
}

// --- 32-block partial barrier, FULLY RELAXED -------------------------------
// All cross-block data (s, bl, counters) moves through agent-scope atomics,
// which are serviced at the LLC coherence point (bypassing the non-coherent
// per-XCD L2s). So no acquire/release cache maintenance is needed:
//  - producer side: __syncthreads() drains vmcnt(0), i.e. every data
//    atomicAdd of the block has COMMITTED at the LLC before thread 0 issues
//    the counter add (also to the LLC -> ordered by the single serialization
//    point).
//  - consumer side: the poll result gates __syncthreads(); reads after it
//    are themselves LLC-serviced atomics, so they observe committed data.
// Round-1 version used ACQUIRE polls + __threadfence: each poll emitted a
// buffer_inv nuking the XCD L2 (~every 130ns x 1024 blocks) -> 17x slowdown.
__device__ __forceinline__ void gbar_arrive(int* c) {
  __syncthreads();  // vmcnt(0): this block's data atomics are committed
  if (threadIdx.x == 0)
    __hip_atomic_fetch_add(c, 1, __ATOMIC_RELAXED, __HIP_MEMORY_SCOPE_AGENT);
}
__device__ __forceinline__ void gbar_wait(int* c) {
  if (threadIdx.x == 0) {
    int it = 0;
    while (__hip_atomic_load(c, __ATOMIC_RELAXED, __HIP_MEMORY_SCOPE_AGENT) < 32) {
      __builtin_amdgcn_s_sleep(1);
      if (++it > (1 << 22)) break;  // safety valve: wrong-answer beats hang
    }
  }
  __syncthreads();
}
__device__ __forceinline__ void gbar(int* c) { gbar_arrive(c); gbar_wait(c); }

// ---------------------------------------------------------------------------
// init: zero bl + s + barrier counters; build Xb[b][k][d] (bf16) and
// WTb[j][k][u][d] (bf16)
// ---------------------------------------------------------------------------
__global__ __launch_bounds__(256) void caps_init(const float* __restrict__ x,
                                                 const float* __restrict__ W,
                                                 float* __restrict__ bl,
                                                 float* __restrict__ s,
                                                 ushort_t* __restrict__ Xb,
                                                 ushort_t* __restrict__ WTb,
                                                 int* __restrict__ cnt) {
  const int g = blockIdx.x * 256 + threadIdx.x;
  if (g < NK * NJ) bl[g] = 0.f;
  if (g < NPH * NB * NU) s[g] = 0.f;
  if (g < NCNT) cnt[g] = 0;
  if (g < (NB * NK * ND) / 8) {  // 589824 groups of 8
    const float4* xp = (const float4*)x + (size_t)g * 2;
    const float4 a = xp[0], b = xp[1];
    uint4 o;
    o.x = (uint)b16(a.x) | ((uint)b16(a.y) << 16);
    o.y = (uint)b16(a.z) | ((uint)b16(a.w) << 16);
    o.z = (uint)b16(b.x) | ((uint)b16(b.y) << 16);
    o.w = (uint)b16(b.z) | ((uint)b16(b.w) << 16);
    ((uint4*)Xb)[g] = o;
  }
  if (g < (NJ * NK * NU * ND) / 8) {  // 184320 groups: (j,k,u) rows of 8 d
    const int u = g & 15;
    const int k = (g >> 4) % NK;
    const int j = g / (NK * NU);
    const float* wp = W + ((size_t)(j * NK + k) * ND) * NU + u;  // d-stride NU
    uint4 o;
    o.x = (uint)b16(wp[0])  | ((uint)b16(wp[16]) << 16);
    o.y = (uint)b16(wp[32]) | ((uint)b16(wp[48]) << 16);
    o.z = (uint)b16(wp[64]) | ((uint)b16(wp[80]) << 16);
    o.w = (uint)b16(wp[96]) | ((uint)b16(wp[112]) << 16);
    ((uint4*)WTb)[g] = o;
  }
}

// ---------------------------------------------------------------------------
// caps_main: persistent cooperative kernel. 1024 blocks (4/CU), block
// (kc,bgi) owns the 16b x 36k tile. X staged to LDS ONCE, W once per j
// (staging overlapped with the cb barrier wait).
// Per phase n=(j,t): [wait cb(n-1)] softmax -> part -> cs barrier ->
// squash -> agree -> arrive cb(n).
// Dependence coloring: s[b][u] couples only same-bgi blocks (32);
// bl[k][j] couples only same-kc blocks (32, all on one XCD).
// ---------------------------------------------------------------------------
__global__ __launch_bounds__(256, 4) void caps_main(
    const ushort_t* __restrict__ Xb, const ushort_t* __restrict__ WTb,
    float* __restrict__ bl, float* __restrict__ s, float* __restrict__ out,
    int* __restrict__ cs, int* __restrict__ cb) {
  __shared__ __align__(16) ushort_t sxu[BT * XPH];  // 9472 B, persistent
  __shared__ __align__(16) ushort_t swu[KT * WPH];  // 9792 B, per-j
  __shared__ float sc[KT];
  __shared__ float svbuf[BT * SVP];                 // 1280 B
  __shared__ float sred[4 * BT * SREDP];            // 5120 B
  const int tid = threadIdx.x;
  const int kc = blockIdx.x & (KCN - 1);
  const int bgi = blockIdx.x >> 5;
  const int b0 = bgi * BT;
  const int k0 = kc * KT;

  {  // stage x ONCE: 576 uint4 (one per (b,k))
    const uint4* gx = (const uint4*)Xb + ((size_t)b0 * NK + k0);
    for (int i = tid; i < BT * KT; i += 256) {
      const int b = i / KT, q = i - b * KT;
      *(uint4*)&sxu[b * XPH + q * 8] = gx[(size_t)b * NK + q];
    }
  }

  const int w = tid >> 6;
  const int lane = tid & 63;
  const int kq = lane >> 4;
  const int bq = (lane >> 2) & 3;
  const int uq = lane & 3;

  for (int n = 0; n < NPH; ++n) {
    const int j = n / 3;
    const int t = n - 3 * j;
    float* sn = s + (size_t)n * NB * NU;

    if (t == 0) {  // stage W for new j (overlaps with the cb wait below).
      // Safe: gbar_arrive(cb[n-1]) did __syncthreads -> all reads of the old
      // swu (agree of n-1) are complete before these writes.
      const uint4* gw = (const uint4*)WTb + ((size_t)j * NK + k0) * NU;
      for (int i = tid; i < KT * NU; i += 256) {
        const int k = i >> 4, u = i & 15;
        *(uint4*)&swu[k * WPH + u * 8] = gw[i];
      }
    }
    if (n > 0) gbar_wait(&cb[(size_t)(n - 1) * KCN + kc]);  // bl col ready

    if (tid < KT) {  // softmax of bl row (k0+tid), column j. LLC-coherent
      // atomic loads (peers' atomicAdds bypassed our L2).
      const float* row = bl + (size_t)(k0 + tid) * NJ;
      float r[NJ];
#pragma unroll
      for (int jj = 0; jj < NJ; ++jj)
        r[jj] = __hip_atomic_load(&row[jj], __ATOMIC_RELAXED,
                                  __HIP_MEMORY_SCOPE_AGENT);
      float mx = r[0];
#pragma unroll
      for (int jj = 1; jj < NJ; ++jj) mx = fmaxf(mx, r[jj]);
      float se = 0.f;
#pragma unroll
      for (int jj = 0; jj < NJ; ++jj) se += __expf(r[jj] - mx);
      sc[tid] = __expf(r[j] - mx) / se;
    }
    __syncthreads();  // sc + swu (+ initial sxu) visible to all

    // ---- part: partial s for this (kc,bgi) tile
    float a[4][4];
#pragma unroll
    for (int i = 0; i < 4; ++i)
#pragma unroll
      for (int m = 0; m < 4; ++m) a[i][m] = 0.f;
#pragma unroll
    for (int it = 0; it < 3; ++it) {
      const int kli = it * 4 + kq;
      if (kli < 9) {
        const int kl = w * 9 + kli;
        const float ck = sc[kl];
        float xd[4][8];
#pragma unroll
        for (int i = 0; i < 4; ++i)
          up8(*(const uint4*)&sxu[(bq * 4 + i) * XPH + kl * 8], xd[i]);
#pragma unroll
        for (int m = 0; m < 4; ++m) {
          float wd[8];
          up8(*(const uint4*)&swu[kl * WPH + (uq * 4 + m) * 8], wd);
#pragma unroll
          for (int i = 0; i < 4; ++i)
            a[i][m] = fmaf(ck, dot8(xd[i], wd), a[i][m]);
        }
      }
    }
#pragma unroll
    for (int i = 0; i < 4; ++i)
#pragma unroll
      for (int m = 0; m < 4; ++m) {
        a[i][m] += __shfl_xor(a[i][m], 16, 64);
        a[i][m] += __shfl_xor(a[i][m], 32, 64);
      }
    if (kq == 0) {
#pragma unroll
      for (int i = 0; i < 4; ++i) {
        const float4 t4 = {a[i][0], a[i][1], a[i][2], a[i][3]};
        *(float4*)&sred[(w * BT + bq * 4 + i) * SREDP + uq * 4] = t4;
      }
    }
    __syncthreads();
    {  // sum 4 waves; accumulate into this phase's s buffer
      const int b = tid >> 4, u = tid & 15;
      const float pv =
          sred[(0 * BT + b) * SREDP + u] + sred[(1 * BT + b) * SREDP + u] +
          sred[(2 * BT + b) * SREDP + u] + sred[(3 * BT + b) * SREDP + u];
      atomicAdd(&sn[(size_t)(b0 + b) * NU + u], pv);
    }
    gbar(&cs[(size_t)n * BGN + bgi]);  // s complete for this b-slice

    {  // squash: v from completed s (LLC-coherent atomic loads)
      const int b = tid >> 4, u = tid & 15;
      const float sval = __hip_atomic_load(&sn[(size_t)(b0 + b) * NU + u],
                                           __ATOMIC_RELAXED,
                                           __HIP_MEMORY_SCOPE_AGENT);
      float sq = sval * sval;
      sq += __shfl_xor(sq, 1, 64);
      sq += __shfl_xor(sq, 2, 64);
      sq += __shfl_xor(sq, 4, 64);
      sq += __shfl_xor(sq, 8, 64);
      const float scale = (sq / (1.f + sq)) / (sqrtf(sq) + EPSQ);
      const float vv = scale * sval;
      svbuf[b * SVP + u] = vv;
      if (t == 2 && kc == 0)
        out[((size_t)(b0 + b) * NJ + j) * NU + u] = vv;
    }
    __syncthreads();

    if (n < NPH - 1) {  // agree (column j, same swu); skip at n=29 (dead)
      float4 vf[4];
#pragma unroll
      for (int i = 0; i < 4; ++i)
        vf[i] = *(const float4*)&svbuf[(bq * 4 + i) * SVP + uq * 4];
#pragma unroll
      for (int it = 0; it < 3; ++it) {
        const int kli = it * 4 + kq;
        if (kli < 9) {
          const int kl = w * 9 + kli;
          float xd[4][8];
#pragma unroll
          for (int i = 0; i < 4; ++i)
            up8(*(const uint4*)&sxu[(bq * 4 + i) * XPH + kl * 8], xd[i]);
          float ag = 0.f;
#pragma unroll
          for (int m = 0; m < 4; ++m) {
            float wd[8];
            up8(*(const uint4*)&swu[kl * WPH + (uq * 4 + m) * 8], wd);
#pragma unroll
            for (int i = 0; i < 4; ++i) {
              const float vm = (m == 0) ? vf[i].x
                             : (m == 1) ? vf[i].y
                             : (m == 2) ? vf[i].z : vf[i].w;
              ag = fmaf(vm, dot8(xd[i], wd), ag);
            }
          }
          ag += __shfl_xor(ag, 1, 64);
          ag += __shfl_xor(ag, 2, 64);
          ag += __shfl_xor(ag, 4, 64);
          ag += __shfl_xor(ag, 8, 64);
          if ((lane & 15) == 0)
            atomicAdd(&bl[(size_t)(k0 + kl) * NJ + j], ag);
        }
      }
      gbar_arrive(&cb[(size_t)n * KCN + kc]);  // bl col j done (this k-slice)
    }
  }
}

// ---------------------------------------------------------------------------
// Fallback path kernels (previous proven 59-launch version), used only if
// cooperative launch is rejected.
// ---------------------------------------------------------------------------
__global__ __launch_bounds__(256, 4) void caps_part(
    const ushort_t* __restrict__ Xb, const ushort_t* __restrict__ WTb,
    const float* __restrict__ bl, float* __restrict__ sn, int js) {
  __shared__ __align__(16) ushort_t sxu[BT * XPH];
  __shared__ __align__(16) ushort_t swu[KT * WPH];
  __shared__ float sc[KT];
  float* sred = (float*)sxu;
  const int tid = threadIdx.x;
  const int kc = blockIdx.x & (KCN - 1);
  const int bgi = blockIdx.x >> 5;
  const int b0 = bgi * BT;
  const int k0 = kc * KT;
  {
    const uint4* gx = (const uint4*)Xb + ((size_t)b0 * NK + k0);
    for (int i = tid; i < BT * KT; i += 256) {
      const int b = i / KT, q = i - b * KT;
      *(uint4*)&sxu[b * XPH + q * 8] = gx[(size_t)b * NK + q];
    }
  }
  {
    const uint4* gw = (const uint4*)WTb + ((size_t)js * NK + k0) * NU;
    for (int i = tid; i < KT * NU; i += 256) {
      const int k = i >> 4, u = i & 15;
      *(uint4*)&swu[k * WPH + u * 8] = gw[i];
    }
  }
  if (tid < KT) {
    const float* row = bl + (size_t)(k0 + tid) * NJ;
    float r[NJ];
#pragma unroll
    for (int jj = 0; jj < NJ; ++jj) r[jj] = row[jj];
    float mx = r[0];
#pragma unroll
    for (int jj = 1; jj < NJ; ++jj) mx = fmaxf(mx, r[jj]);
    float se = 0.f;
#pragma unroll
    for (int jj = 0; jj < NJ; ++jj) se += __expf(r[jj] - mx);
    sc[tid] = __expf(r[js] - mx) / se;
  }
  __syncthreads();
  const int w = tid >> 6;
  const int lane = tid & 63;
  const int kq = lane >> 4;
  const int bq = (lane >> 2) & 3;
  const int uq = lane & 3;
  float a[4][4];
#pragma unroll
  for (int i = 0; i < 4; ++i)
#pragma unroll
    for (int m = 0; m < 4; ++m) a[i][m] = 0.f;
#pragma unroll
  for (int it = 0; it < 3; ++it) {
    const int kli = it * 4 + kq;
    if (kli < 9) {
      const int kl = w * 9 + kli;
      const float ck = sc[kl];
      float xd[4][8];
#pragma unroll
      for (int i = 0; i < 4; ++i)
        up8(*(const uint4*)&sxu[(bq * 4 + i) * XPH + kl * 8], xd[i]);
#pragma unroll
      for (int m = 0; m < 4; ++m) {
        float wd[8];
        up8(*(const uint4*)&swu[kl * WPH + (uq * 4 + m) * 8], wd);
#pragma unroll
        for (int i = 0; i < 4; ++i)
          a[i][m] = fmaf(ck, dot8(xd[i], wd), a[i][m]);
      }
    }
  }
#pragma unroll
  for (int i = 0; i < 4; ++i)
#pragma unroll
    for (int m = 0; m < 4; ++m) {
      a[i][m] += __shfl_xor(a[i][m], 16, 64);
      a[i][m] += __shfl_xor(a[i][m], 32, 64);
    }
  __syncthreads();
  if (kq == 0) {
#pragma unroll
    for (int i = 0; i < 4; ++i) {
      const float4 t4 = {a[i][0], a[i][1], a[i][2], a[i][3]};
      *(float4*)&sred[(w * BT + bq * 4 + i) * SREDP + uq * 4] = t4;
    }
  }
  __syncthreads();
  {
    const int b = tid >> 4, u = tid & 15;
    const float sv =
        sred[(0 * BT + b) * SREDP + u] + sred[(1 * BT + b) * SREDP + u] +
        sred[(2 * BT + b) * SREDP + u] + sred[(3 * BT + b) * SREDP + u];
    atomicAdd(&sn[(size_t)(b0 + b) * NU + u], sv);
  }
}

__global__ __launch_bounds__(256, 4) void caps_agp(
    const ushort_t* __restrict__ Xb, const ushort_t* __restrict__ WTb,
    const float* __restrict__ sprev, float* __restrict__ bl,
    float* __restrict__ out, int ja, int wout) {
  __shared__ __align__(16) ushort_t sxu[BT * XPH];
  __shared__ __align__(16) ushort_t swu[KT * WPH];
  __shared__ float sv[BT * SVP];
  const int tid = threadIdx.x;
  const int kc = blockIdx.x & (KCN - 1);
  const int bgi = blockIdx.x >> 5;
  const int b0 = bgi * BT;
  const int k0 = kc * KT;
  {
    const uint4* gx = (const uint4*)Xb + ((size_t)b0 * NK + k0);
    for (int i = tid; i < BT * KT; i += 256) {
      const int b = i / KT, q = i - b * KT;
      *(uint4*)&sxu[b * XPH + q * 8] = gx[(size_t)b * NK + q];
    }
  }
  {
    const uint4* gw = (const uint4*)WTb + ((size_t)ja * NK + k0) * NU;
    for (int i = tid; i < KT * NU; i += 256) {
      const int k = i >> 4, u = i & 15;
      *(uint4*)&swu[k * WPH + u * 8] = gw[i];
    }
  }
  {
    const int b = tid >> 4, u = tid & 15;
    const float s = sprev[(size_t)(b0 + b) * NU + u];
    float sq = s * s;
    sq += __shfl_xor(sq, 1, 64);
    sq += __shfl_xor(sq, 2, 64);
    sq += __shfl_xor(sq, 4, 64);
    sq += __shfl_xor(sq, 8, 64);
    const float scale = (sq / (1.f + sq)) / (sqrtf(sq) + EPSQ);
    const float vv = scale * s;
    sv[b * SVP + u] = vv;
    if (wout && kc == 0) out[((size_t)(b0 + b) * NJ + ja) * NU + u] = vv;
  }
  __syncthreads();
  const int w = tid >> 6;
  const int lane = tid & 63;
  const int kq = lane >> 4;
  const int bq = (lane >> 2) & 3;
  const int uq = lane & 3;
  float4 vf[4];
#pragma unroll
  for (int i = 0; i < 4; ++i)
    vf[i] = *(const float4*)&sv[(bq * 4 + i) * SVP + uq * 4];
#pragma unroll
  for (int it = 0; it < 3; ++it) {
    const int kli = it * 4 + kq;
    if (kli < 9) {
      const int kl = w * 9 + kli;
      float xd[4][8];
#pragma unroll
      for (int i = 0; i < 4; ++i)
        up8(*(const uint4*)&sxu[(bq * 4 + i) * XPH + kl * 8], xd[i]);
      float ag = 0.f;
#pragma unroll
      for (int m = 0; m < 4; ++m) {
        float wd[8];
        up8(*(const uint4*)&swu[kl * WPH + (uq * 4 + m) * 8], wd);
#pragma unroll
        for (int i = 0; i < 4; ++i) {
          const float vm = (m == 0) ? vf[i].x
                         : (m == 1) ? vf[i].y
                         : (m == 2) ? vf[i].z : vf[i].w;
          ag = fmaf(vm, dot8(xd[i], wd), ag);
        }
      }
      ag += __shfl_xor(ag, 1, 64);
      ag += __shfl_xor(ag, 2, 64);
      ag += __shfl_xor(ag, 4, 64);
      ag += __shfl_xor(ag, 8, 64);
      if ((lane & 15) == 0)
        atomicAdd(&bl[(size_t)(k0 + kl) * NJ + ja], ag);
    }
  }
}

__global__ __launch_bounds__(256) void caps_finout(const float* __restrict__ slast,
                                                   float* __restrict__ out) {
  const int g = blockIdx.x * 256 + threadIdx.x;
  const int b = g >> 4, u = g & 15;
  const float s = slast[(size_t)b * NU + u];
  float sq = s * s;
  sq += __shfl_xor(sq, 1, 64);
  sq += __shfl_xor(sq, 2, 64);
  sq += __shfl_xor(sq, 4, 64);
  sq += __shfl_xor(sq, 8, 64);
  const float scale = (sq / (1.f + sq)) / (sqrtf(sq) + EPSQ);
  out[((size_t)b * NJ + (NJ - 1)) * NU + u] = scale * s;
}

// ---------------------------------------------------------------------------
extern "C" void kernel_launch(void* const* d_in, const int* in_sizes, int n_in,
                              void* d_out, int out_size, void* d_ws,
                              size_t ws_size, hipStream_t stream) {
  (void)in_sizes; (void)n_in; (void)out_size; (void)ws_size;
  const float* x = (const float*)d_in[0];   // [512][1152][8][1] fp32
  const float* W = (const float*)d_in[1];   // [10][1152][8][16] fp32
  float* out = (float*)d_out;               // [512][10][16][1] fp32
  float* ws = (float*)d_ws;
  float* bl = ws + OFF_BL;
  float* s  = ws + OFF_S;
  ushort_t* Xb  = (ushort_t*)(ws + OFF_XB);
  ushort_t* WTb = (ushort_t*)(ws + OFF_WTB);
  int* cs = (int*)(ws + OFF_CNT);           // [NPH][BGN]
  int* cb = cs + NPH * BGN;                 // [NPH][KCN]

  caps_init<<<(NB * NK * ND / 8 + 255) / 256, 256, 0, stream>>>(x, W, bl, s,
                                                                Xb, WTb, cs);

  void* args[] = {&Xb, &WTb, &bl, &s, &out, &cs, &cb};
  hipError_t err = hipLaunchCooperativeKernel(
      (const void*)caps_main, dim3(KCN * BGN), dim3(256), args, 0, stream);

  if (err != hipSuccess) {
    // Fallback: proven 59-launch sequence (identical numerics).
    for (int n = 0; n < NPH; ++n) {
      const int j = n / 3, t = n - 3 * j;
      if (n > 0) {
        const int ja = (t == 0) ? (j - 1) : j;
        caps_agp<<<KCN * BGN, 256, 0, stream>>>(
            Xb, WTb, s + (size_t)(n - 1) * NB * NU, bl, out, ja,
            (t == 0) ? 1 : 0);
      }
      caps_part<<<KCN * BGN, 256, 0, stream>>>(Xb, WTb, bl,
                                               s + (size_t)n * NB * NU, j);
    }
    caps_finout<<<(NB * NU) / 256, 256, 0, stream>>>(
        s + (size_t)(NPH - 1) * NB * NU, out);
  }
}